// Round 5
// baseline (3440.265 us; speedup 1.0000x reference)
//
#include <hip/hip_runtime.h>
#include <hip/hip_bf16.h>
#include <string.h>

#define NPT   16384
#define NBAT  16
#define CH    288
#define SP    256
#define KS    16
#define OFF_FEAT 12288L
#define OFF_IND  1191936L

// ---------- helpers ----------
__device__ __forceinline__ float bfbits(unsigned short u){
  unsigned int x = ((unsigned int)u) << 16; float f; __builtin_memcpy(&f,&x,4); return f;
}
__device__ __forceinline__ float ldf(const void* p, long i, int isb){
  if (isb) return __bfloat162float(((const __hip_bfloat16*)p)[i]);
  return ((const float*)p)[i];
}
__device__ __forceinline__ void sto(void* p, long i, float v, int isb){
  if (isb) ((__hip_bfloat16*)p)[i] = __float2bfloat16(v);
  else     ((float*)p)[i] = v;
}
__device__ __forceinline__ void gload_lds(const void* g, void* l){
  __builtin_amdgcn_global_load_lds((const __attribute__((address_space(1))) void*)g,
      (__attribute__((address_space(3))) void*)l, 16, 0, 0);
}
__device__ __forceinline__ unsigned spread4(unsigned x){
  return (x&1u) | ((x&2u)<<2) | ((x&4u)<<4) | ((x&8u)<<6);
}

typedef __attribute__((ext_vector_type(8))) short bf16x8;
typedef __attribute__((ext_vector_type(4))) float f32x4;
typedef __attribute__((ext_vector_type(2))) float f32x2;

// u64 max via DPP row_ror (VALU cross-lane, no DS). Max is associative+commutative,
// so any reduce network gives the bit-exact same result as a shfl butterfly.
template<int CTRL>
__device__ __forceinline__ unsigned long long ror_max64(unsigned long long k){
  int lo2 = __builtin_amdgcn_update_dpp(0, (int)(unsigned)k, CTRL, 0xf, 0xf, false);
  int hi2 = __builtin_amdgcn_update_dpp(0, (int)(unsigned)(k>>32), CTRL, 0xf, 0xf, false);
  unsigned long long o = ((unsigned long long)(unsigned)hi2 << 32) | (unsigned)lo2;
  return o > k ? o : k;
}
__device__ __forceinline__ unsigned long long rowmax64(unsigned long long k){
  k = ror_max64<0x121>(k);   // row_ror:1
  k = ror_max64<0x122>(k);   // row_ror:2
  k = ror_max64<0x124>(k);   // row_ror:4
  k = ror_max64<0x128>(k);   // row_ror:8  -> every lane holds max of its 16-lane row
  return k;
}
__device__ __forceinline__ unsigned long long rl64(unsigned long long v, int l){
  unsigned lo = (unsigned)__builtin_amdgcn_readlane((int)(unsigned)v, l);
  unsigned hi = (unsigned)__builtin_amdgcn_readlane((int)(unsigned)(v>>32), l);
  return (((unsigned long long)hi)<<32) | lo;
}

// ---------- 0. input dtype detection ----------
__global__ void detect_k(const void* __restrict__ xyz, int* __restrict__ flag){
  __shared__ float red[256];
  const int t = threadIdx.x;
  const unsigned short* u = (const unsigned short*)xyz;
  float m = 0.f;
  for (int i = t; i < 4096; i += 256){
    float f = fabsf(bfbits(u[i]));
    if (f != f) f = 1e30f;
    m = fmaxf(m, f);
  }
  red[t] = m; __syncthreads();
  for (int s = 128; s; s >>= 1){ if (t < s) red[t] = fmaxf(red[t], red[t+s]); __syncthreads(); }
  if (t == 0) *flag = (red[0] < 2.0f) ? 1 : 0;
}

// ---------- 0b. xyz -> f32 SoA ----------
__global__ __launch_bounds__(256) void cvtxyz_k(const void* __restrict__ xyz,
    const int* __restrict__ flag, float* __restrict__ X, float* __restrict__ Y,
    float* __restrict__ Z){
  const int n = blockIdx.x*256 + threadIdx.x;       // < 262144 points
  const int isb = *flag;
  float x = ldf(xyz, (long)n*3+0, isb);
  float y = ldf(xyz, (long)n*3+1, isb);
  float z = ldf(xyz, (long)n*3+2, isb);
  X[n] = x; Y[n] = y; Z[n] = z;
}

// ---------- 0c. W -> bf16 [288][296] + BN scale/shift ----------
__global__ __launch_bounds__(256) void cvtw_k(const void* __restrict__ W,
    const void* __restrict__ g, const void* __restrict__ bb,
    const void* __restrict__ m, const void* __restrict__ v,
    const int* __restrict__ flag, __hip_bfloat16* __restrict__ Wbf,
    float* __restrict__ scale, float* __restrict__ shift, int Kin){
  const int isb = *flag;
  const int idx = blockIdx.x*256 + threadIdx.x;
  if (idx < 288*296){
    int o = idx / 296, k = idx - o*296;
    float val = (k < Kin) ? ldf(W, (long)o*Kin + k, isb) : 0.f;
    Wbf[idx] = __float2bfloat16(val);
  }
  if (idx < 288){
    float sc = ldf(g, idx, isb) * rsqrtf(ldf(v, idx, isb) + 1e-5f);
    scale[idx] = sc;
    shift[idx] = ldf(bb, idx, isb) - ldf(m, idx, isb)*sc;
  }
}

// ---------- 0d. Morton bucket sort (per batch): spatial clustering for FPS pruning ----------
__global__ __launch_bounds__(1024) void sort_k(const float* __restrict__ X,
    const float* __restrict__ Y, const float* __restrict__ Z,
    float* __restrict__ X2, float* __restrict__ Y2, float* __restrict__ Z2,
    int* __restrict__ I2){
  __shared__ int hist[4096];
  __shared__ int wtot[16];
  const int b = blockIdx.x, t = threadIdx.x, base = b*NPT;
  for (int j = t; j < 4096; j += 1024) hist[j] = 0;
  __syncthreads();
  int cell[16]; float lx[16], ly[16], lz[16];
  #pragma unroll
  for (int i=0;i<16;i++){
    const int id = t + i*1024;
    float x = X[base+id], y = Y[base+id], z = Z[base+id];
    lx[i]=x; ly[i]=y; lz[i]=z;
    int cx = (int)(x*16.f); cx = cx<0?0:(cx>15?15:cx);
    int cy = (int)(y*16.f); cy = cy<0?0:(cy>15?15:cy);
    int cz = (int)(z*16.f); cz = cz<0?0:(cz>15?15:cz);
    cell[i] = (int)(spread4((unsigned)cx) | (spread4((unsigned)cy)<<1) | (spread4((unsigned)cz)<<2));
    atomicAdd(&hist[cell[i]], 1);
  }
  __syncthreads();
  int s0 = hist[t*4], s1 = hist[t*4+1], s2 = hist[t*4+2], s3 = hist[t*4+3];
  int ls = s0+s1+s2+s3;
  int sc = ls;
  #pragma unroll
  for (int off=1; off<64; off<<=1){
    int o = __shfl_up(sc, off, 64);
    if ((t&63) >= off) sc += o;
  }
  if ((t&63) == 63) wtot[t>>6] = sc;
  __syncthreads();
  int wpre = 0;
  #pragma unroll
  for (int w=0; w<16; w++) wpre += (w < (t>>6)) ? wtot[w] : 0;
  const int ebase = wpre + sc - ls;
  hist[t*4]   = ebase;
  hist[t*4+1] = ebase + s0;
  hist[t*4+2] = ebase + s0 + s1;
  hist[t*4+3] = ebase + s0 + s1 + s2;
  __syncthreads();
  #pragma unroll
  for (int i=0;i<16;i++){
    const int dst = atomicAdd(&hist[cell[i]], 1);
    X2[base+dst] = lx[i]; Y2[base+dst] = ly[i]; Z2[base+dst] = lz[i];
    I2[base+dst] = t + i*1024;
  }
}

// ---------- 1. FPS: DPP argmax + pair prune + winner-coords carried in LDS ----------
// Winner lane (unique: keys unique) writes its (x,y,z) to slotc[p][wid] each iter;
// post-barrier ballot finds the winning wave -> one uniform ds_read_b128 replaces
// the dependent global P4 load. Stale-on-skip is valid: skipped waves' wk/coords
// are unchanged by construction (prune guarantees fminf is a bitwise no-op).
__global__ __launch_bounds__(1024) __attribute__((amdgpu_waves_per_eu(4,4)))
void fps_k(const float* __restrict__ X, const float* __restrict__ Y,
    const float* __restrict__ Z,
    const float* __restrict__ X2, const float* __restrict__ Y2,
    const float* __restrict__ Z2, const int* __restrict__ I2,
    const int* __restrict__ flag, float* __restrict__ nxyz, void* __restrict__ dout){
  #pragma clang fp contract(off)
  const int b = blockIdx.x, t = threadIdx.x;
  const int base = b*NPT;
  const int lane = t & 63, wid = t >> 6;
  f32x2 px[8], py[8], pz[8], ds[8];
  unsigned li2[8];
  unsigned long long pk[8];
  const int p0 = base + wid*1024 + lane;
  #pragma unroll
  for (int j=0;j<8;j++){
    px[j] = (f32x2){X2[p0 + (2*j)*64], X2[p0 + (2*j+1)*64]};
    py[j] = (f32x2){Y2[p0 + (2*j)*64], Y2[p0 + (2*j+1)*64]};
    pz[j] = (f32x2){Z2[p0 + (2*j)*64], Z2[p0 + (2*j+1)*64]};
    unsigned a = 16383u - (unsigned)I2[p0 + (2*j)*64];
    unsigned c = 16383u - (unsigned)I2[p0 + (2*j+1)*64];
    li2[j] = a | (c<<16);
    ds[j] = (f32x2){1e10f, 1e10f};
    pk[j] = 0ull;
  }
  // per-pair bboxes; lane holds pair (lane&7)'s bbox
  float pnx=0.f, pxx=0.f, pny=0.f, pxy=0.f, pnz=0.f, pxz=0.f;
  const int myp = lane & 7;
  #pragma unroll
  for (int j=0;j<8;j++){
    float nx = fminf(px[j].x,px[j].y), xx = fmaxf(px[j].x,px[j].y);
    float ny = fminf(py[j].x,py[j].y), xy = fmaxf(py[j].x,py[j].y);
    float nz = fminf(pz[j].x,pz[j].y), xz = fmaxf(pz[j].x,pz[j].y);
    #pragma unroll
    for (int off=32; off; off>>=1){
      nx = fminf(nx, __shfl_xor(nx, off, 64)); xx = fmaxf(xx, __shfl_xor(xx, off, 64));
      ny = fminf(ny, __shfl_xor(ny, off, 64)); xy = fmaxf(xy, __shfl_xor(xy, off, 64));
      nz = fminf(nz, __shfl_xor(nz, off, 64)); xz = fmaxf(xz, __shfl_xor(xz, off, 64));
    }
    if (myp == j){ pnx=nx; pxx=xx; pny=ny; pxy=xy; pnz=nz; pxz=xz; }
  }
  __shared__ unsigned long long slot[2][16];
  __shared__ float4 slotc[2][16];
  __shared__ float ox[SP], oy[SP], oz[SP];
  __shared__ int   oi[SP];
  float cx = X[base], cy = Y[base], cz = Z[base];
  int cur = 0;
  unsigned long long wk = 0ull, best = 0ull;
  int bj = 0;
  float wavemax = 1e30f;
  for (int it=0; it<SP; it++){
    if (t == 0){ ox[it]=cx; oy[it]=cy; oz[it]=cz; oi[it]=cur; }
    float ddx = fmaxf(fmaxf(pnx-cx, cx-pxx), 0.f);
    float ddy = fmaxf(fmaxf(pny-cy, cy-pxy), 0.f);
    float ddz = fmaxf(fmaxf(pnz-cz, cz-pxz), 0.f);
    float lb = ddx*ddx + ddy*ddy; lb = lb + ddz*ddz;
    unsigned mask = (unsigned)__ballot(!(lb * 0.9999f > wavemax)) & 0xffu;
    mask = (unsigned)__builtin_amdgcn_readfirstlane((int)mask);
    if (mask){
      const f32x2 Cx = {cx,cx}, Cy = {cy,cy}, Cz = {cz,cz};
      #define UPD(j) if (mask & (1u<<(j))) { \
        f32x2 dx = px[j]-Cx, dy = py[j]-Cy, dz = pz[j]-Cz; \
        f32x2 m0 = dx*dx, m1 = dy*dy, m2 = dz*dz; \
        f32x2 d2 = (m0+m1)+m2; \
        f32x2 dn = __builtin_elementwise_min(ds[j], d2); \
        ds[j] = dn; \
        unsigned long long k0 = ((unsigned long long)__float_as_uint(dn.x)<<32) | (unsigned long long)(li2[j] & 0xFFFFu); \
        unsigned long long k1 = ((unsigned long long)__float_as_uint(dn.y)<<32) | (unsigned long long)(li2[j] >> 16); \
        pk[j] = (k0 > k1) ? k0 : k1; }
      UPD(0) UPD(1) UPD(2) UPD(3) UPD(4) UPD(5) UPD(6) UPD(7)
      #undef UPD
      best = pk[0]; bj = 0;
      #pragma unroll
      for (int j=1;j<8;j++){ if (pk[j] > best){ best = pk[j]; bj = j; } }
      unsigned long long rbest = rowmax64(best);
      unsigned long long r0 = rl64(rbest, 0),  r1 = rl64(rbest, 16);
      unsigned long long r2 = rl64(rbest, 32), r3 = rl64(rbest, 48);
      unsigned long long a01 = (r0 > r1) ? r0 : r1;
      unsigned long long a23 = (r2 > r3) ? r2 : r3;
      wk = (a01 > a23) ? a01 : a23;
      wavemax = __uint_as_float((unsigned)(wk >> 32));
    }
    const int p = it & 1;
    if (lane == 0) slot[p][wid] = wk;
    if (best == wk){
      // unique winner lane; bj/ds/li2 persist across skipped iterations
      unsigned long long k0 = ((unsigned long long)__float_as_uint(ds[bj].x)<<32)
                            | (unsigned long long)(li2[bj] & 0xFFFFu);
      bool ex = (k0 == wk);
      slotc[p][wid] = make_float4(ex ? px[bj].x : px[bj].y,
                                  ex ? py[bj].x : py[bj].y,
                                  ex ? pz[bj].x : pz[bj].y, 0.f);
    }
    __syncthreads();
    unsigned long long sv = slot[p][lane & 15];
    unsigned long long g = rowmax64(sv);
    unsigned long long wb = __ballot(sv == g);
    int w = ((int)__builtin_ctzll(wb)) & 15;
    w = __builtin_amdgcn_readfirstlane(w);
    float4 cc = slotc[p][w];
    cur = 16383 - (int)(unsigned)g;
    cur = __builtin_amdgcn_readfirstlane(cur);
    cx = cc.x; cy = cc.y; cz = cc.z;
  }
  __syncthreads();
  if (t < SP){
    const int isb = *flag;
    const long bs = (long)b*SP + t;
    float fx=ox[t], fy=oy[t], fz=oz[t]; int ii=oi[t];
    nxyz[bs*3+0]=fx; nxyz[bs*3+1]=fy; nxyz[bs*3+2]=fz;
    sto(dout, bs*3+0, fx, isb);
    sto(dout, bs*3+1, fy, isb);
    sto(dout, bs*3+2, fz, isb);
    sto(dout, OFF_IND + bs, (float)ii, isb);
  }
}

// ---------- 2. ball query (SoA f32) ----------
__global__ __launch_bounds__(256) void ballq_k(const float* __restrict__ X,
    const float* __restrict__ Y, const float* __restrict__ Z,
    const float* __restrict__ nxyz, int* __restrict__ bidx){
  #pragma clang fp contract(off)
  const int gw = (blockIdx.x*256 + threadIdx.x) >> 6;
  const int lane = threadIdx.x & 63;
  const int b = gw >> 8, base = b*NPT;
  const float cx = nxyz[gw*3+0], cy = nxyz[gw*3+1], cz = nxyz[gw*3+2];
  int cnt = 0, first = 0; bool havef = false;
  for (int st = 0; st < NPT && cnt < KS; st += 64){
    const int id = st + lane;
    float dx = X[base+id]-cx, dy = Y[base+id]-cy, dz = Z[base+id]-cz;
    float d2 = dx*dx + dy*dy; d2 = d2 + dz*dz;
    unsigned long long mk = __ballot(d2 <= 0.09f);
    if (mk){
      if (!havef){ first = st + __builtin_ctzll(mk); havef = true; }
      int rank = cnt + __popcll(mk & ((1ull<<lane)-1ull));
      if (((mk>>lane)&1ull) && rank < KS) bidx[gw*KS + rank] = id;
      cnt += __popcll(mk);
    }
  }
  if (cnt < KS && lane >= cnt && lane < KS) bidx[gw*KS + lane] = first;
}

// ---------- 3a. inverted index: bucket 4096 slots/batch by id>>6 (256 ranges) ----------
// Exact counting sort; within-bucket order is irrelevant (each slot written once).
__global__ __launch_bounds__(1024) void invb_k(const int* __restrict__ bidx,
    int* __restrict__ inv, int* __restrict__ bstart){
  __shared__ int hist[256];
  __shared__ int off[256];
  const int b = blockIdx.x, t = threadIdx.x;
  if (t < 256) hist[t] = 0;
  __syncthreads();
  int id_[4];
  #pragma unroll
  for (int i=0;i<4;i++){
    id_[i] = bidx[b*4096 + t + i*1024];
    atomicAdd(&hist[id_[i] >> 6], 1);
  }
  __syncthreads();
  if (t < 64){
    int h0=hist[t*4], h1=hist[t*4+1], h2=hist[t*4+2], h3=hist[t*4+3];
    int ls = h0+h1+h2+h3, sc = ls;
    #pragma unroll
    for (int o=1; o<64; o<<=1){
      int ov = __shfl_up(sc, o, 64);
      if (t >= o) sc += ov;
    }
    int excl = sc - ls;
    off[t*4]   = excl;
    off[t*4+1] = excl + h0;
    off[t*4+2] = excl + h0 + h1;
    off[t*4+3] = excl + h0 + h1 + h2;
    bstart[b*256 + t*4]   = b*4096 + excl;
    bstart[b*256 + t*4+1] = b*4096 + excl + h0;
    bstart[b*256 + t*4+2] = b*4096 + excl + h0 + h1;
    bstart[b*256 + t*4+3] = b*4096 + excl + h0 + h1 + h2;
  }
  if (b == 0 && t == 0) bstart[4096] = 65536;
  __syncthreads();
  #pragma unroll
  for (int i=0;i<4;i++){
    const int sl = t + i*1024;
    const int pos = atomicAdd(&off[id_[i] >> 6], 1);
    inv[b*4096 + pos] = sl | (id_[i] << 12);       // 12b slot | 14b id
  }
}

// ---------- 3b. bucketed gather: stage [288][64] feat slab coalesced, emit h0 rows ----------
// h0 content bit-identical to the old gather (same bf16 values, same xyz math).
__global__ __launch_bounds__(256) void gath2_k(const void* __restrict__ feat,
    const void* __restrict__ xyz, const int* __restrict__ flag,
    const int* __restrict__ inv, const int* __restrict__ bstart,
    const float* __restrict__ nxyz, __hip_bfloat16* __restrict__ h0){
  __shared__ __hip_bfloat16 tile[CH*66];           // [c][66], pad 2 -> conflict-free
  const int isb = *flag;
  const int bid = blockIdx.x;                      // 4096 = 16 batches x 256 ranges
  const int b = bid >> 8, r = bid & 255;
  const int t = threadIdx.x;
  const int n0 = r*64, ln = t & 63, c0 = t >> 6;
  const long fb = (long)b*CH*NPT;
  for (int c = c0; c < CH; c += 4)
    tile[c*66 + ln] = __float2bfloat16(ldf(feat, fb + (long)c*NPT + n0 + ln, isb));
  __syncthreads();
  const int s0 = bstart[bid], s1 = bstart[bid+1];
  const int q = t & 3;
  for (int w0 = s0 + (t>>2); w0 < s1; w0 += 64){
    const int pv = inv[w0];
    const int sl = pv & 0xFFF;
    const int id = pv >> 12;
    const int col = id & 63;
    const long s = (long)b*4096 + sl;
    const int ctr = (int)(s >> 4);
    uint4* dst = (uint4*)(h0 + s*296);
    const int cbeg = q*9, cend = (q==3) ? 37 : q*9+9;
    for (int ch = cbeg; ch < cend; ch++){
      unsigned short u[8];
      #pragma unroll
      for (int e=0;e<8;e++){
        const int hc = ch*8 + e;
        unsigned short us = 0;
        if (hc < 3){
          float vv = (ldf(xyz, ((long)b*NPT + id)*3 + hc, isb) - nxyz[(long)ctr*3 + hc]) / 0.3f;
          __hip_bfloat16 hb = __float2bfloat16(vv); __builtin_memcpy(&us,&hb,2);
        } else if (hc < 291){
          __hip_bfloat16 hb = tile[(hc-3)*66 + col]; __builtin_memcpy(&us,&hb,2);
        }
        u[e] = us;
      }
      uint4 pkv; __builtin_memcpy(&pkv, u, 16);
      dst[ch] = pkv;
    }
  }
}

// ---------- 4. MFMA GEMM: Out[n][o] = relu(BN(sum_k A[n][k]*W[o][k])) ----------
__global__ __launch_bounds__(256, 2) void gemm_k(
    const __hip_bfloat16* __restrict__ A, int astr,
    const __hip_bfloat16* __restrict__ W,
    const float* __restrict__ scale, const float* __restrict__ shift,
    __hip_bfloat16* __restrict__ Out, int ostr,
    int ktiles, int kvalid){
  extern __shared__ char lds[];
  const int t = threadIdx.x, lane = t & 63, wid = t >> 6;
  const int wm = wid & 1, wo = wid >> 1;
  const int bx = blockIdx.x, by = blockIdx.y;
  {
    const char* src = (const char*)(A + (long)bx*128*astr);
    const int chunks = (128*astr*2) >> 10;
    for (int c = wid; c < chunks; c += 4)
      gload_lds(src + c*1024 + lane*16, lds + c*1024);
  }
  f32x4 acc[4][3];
  #pragma unroll
  for (int mf=0; mf<4; mf++)
    #pragma unroll
    for (int of=0; of<3; of++) acc[mf][of] = (f32x4){0.f,0.f,0.f,0.f};

  const int mrow  = wm*64 + (lane & 15);
  const int kg    = (lane >> 4) * 8;
  const int obase = by*96 + wo*48 + (lane & 15);
  __syncthreads();

  for (int kt = 0; kt < ktiles; kt++){
    const int k0 = kt*32 + kg;
    const bool z = (k0 >= kvalid);
    const int k0c = z ? 0 : k0;
    bf16x8 a[4], bf[3];
    #pragma unroll
    for (int mf=0; mf<4; mf++)
      a[mf] = *(const bf16x8*)(lds + ((long)(mrow + mf*16)*astr + k0c)*2);
    if (z){
      bf16x8 zz = {0,0,0,0,0,0,0,0};
      #pragma unroll
      for (int mf=0; mf<4; mf++) a[mf] = zz;
    }
    #pragma unroll
    for (int of=0; of<3; of++)
      bf[of] = *(const bf16x8*)(W + (long)(obase + of*16)*296 + k0c);
    #pragma unroll
    for (int mf=0; mf<4; mf++)
      #pragma unroll
      for (int of=0; of<3; of++)
        acc[mf][of] = __builtin_amdgcn_mfma_f32_16x16x32_bf16(a[mf], bf[of], acc[mf][of], 0, 0, 0);
  }

  float sc[3], sh[3];
  #pragma unroll
  for (int of=0; of<3; of++){ sc[of] = scale[obase + of*16]; sh[of] = shift[obase + of*16]; }
  #pragma unroll
  for (int mf=0; mf<4; mf++)
    #pragma unroll
    for (int of=0; of<3; of++)
      #pragma unroll
      for (int r=0; r<4; r++){
        const long row = (long)bx*128 + wm*64 + mf*16 + (lane>>4)*4 + r;
        const int o = obase + of*16;
        float vv = acc[mf][of][r]*sc[of] + sh[of];
        Out[row*ostr + o] = __float2bfloat16(fmaxf(vv, 0.f));
      }
}

// ---------- 5. maxpool over k: h[n][288] -> out[b][o][s] ----------
__global__ __launch_bounds__(256) void maxk_k(const __hip_bfloat16* __restrict__ h,
    const int* __restrict__ flag, void* __restrict__ dout){
  __shared__ __hip_bfloat16 tile[128*288];
  const int isb = *flag;
  const int t = threadIdx.x;
  const int b = blockIdx.x >> 5, s0 = (blockIdx.x & 31)*8;
  const long n0 = (long)b*4096 + (long)s0*16;
  {
    const char* src = (const char*)(h + n0*288);
    for (int c = (t>>6); c < 72; c += 4)
      gload_lds(src + c*1024 + (t&63)*16, (char*)tile + c*1024);
  }
  __syncthreads();
  for (int o = t; o < 288; o += 256){
    float mx[8];
    #pragma unroll
    for (int sl=0; sl<8; sl++){
      float m = -1e30f;
      #pragma unroll
      for (int kk=0; kk<16; kk++)
        m = fmaxf(m, __bfloat162float(tile[(sl*16 + kk)*288 + o]));
      mx[sl] = m;
    }
    const long e0 = OFF_FEAT + (long)b*73728 + (long)o*256 + s0;
    if (isb){
      unsigned short u[8];
      #pragma unroll
      for (int sl=0; sl<8; sl++){
        __hip_bfloat16 hb = __float2bfloat16(mx[sl]);
        __builtin_memcpy(&u[sl], &hb, 2);
      }
      uint4 pk; __builtin_memcpy(&pk, u, 16);
      *(uint4*)((__hip_bfloat16*)dout + e0) = pk;
    } else {
      float* fo = (float*)dout + e0;
      *(float4*)fo     = make_float4(mx[0],mx[1],mx[2],mx[3]);
      *(float4*)(fo+4) = make_float4(mx[4],mx[5],mx[6],mx[7]);
    }
  }
}

extern "C" void kernel_launch(void* const* d_in, const int* in_sizes, int n_in,
                              void* d_out, int out_size, void* d_ws, size_t ws_size,
                              hipStream_t stream){
  const void* xyz  = d_in[0];
  const void* feat = d_in[1];
  const void* W0 = d_in[2];  const void* g0 = d_in[3];  const void* b0 = d_in[4];
  const void* m0 = d_in[5];  const void* v0 = d_in[6];
  const void* W1 = d_in[7];  const void* g1 = d_in[8];  const void* b1 = d_in[9];
  const void* m1 = d_in[10]; const void* v1 = d_in[11];
  const void* W2 = d_in[12]; const void* g2 = d_in[13]; const void* b2 = d_in[14];
  const void* m2 = d_in[15]; const void* v2 = d_in[16];

  char* ws = (char*)d_ws;
  int*   flag  = (int*)ws;                                   // [0,64)
  float* sc0   = (float*)(ws + 64);
  float* sh0   = sc0 + 288;
  float* sc1   = sc0 + 576;  float* sh1 = sc0 + 864;
  float* sc2   = sc0 + 1152; float* sh2 = sc0 + 1440;
  __hip_bfloat16* Wb0 = (__hip_bfloat16*)(ws + 7040);        // 288*296*2 each
  __hip_bfloat16* Wb1 = Wb0 + 288*296;
  __hip_bfloat16* Wb2 = Wb1 + 288*296;                       // ends @ 518528
  float* nxyz = (float*)(ws + 518656);                       // -> 567808
  int*   bidx = (int*)(ws + 567808);                         // -> 829952
  float* X    = (float*)(ws + 1048576);                      // overlaid with bufA (dead after gath2 slab... used by ballq only)
  float* Y    = X + NBAT*NPT;
  float* Z    = Y + NBAT*NPT;
  __hip_bfloat16* bufA = (__hip_bfloat16*)(ws + 1048576);    // [65536][296] = 38797312
  __hip_bfloat16* bufB = (__hip_bfloat16*)(ws + 1048576 + 38797312); // [65536][288]
  // overlays on bufB (all dead before gemm#1 writes bufB):
  float* X2 = (float*)bufB;                                  // fps inputs (dead after fps)
  float* Y2 = X2 + NBAT*NPT;
  float* Z2 = Y2 + NBAT*NPT;
  int*   I2 = (int*)(Z2 + NBAT*NPT);
  int*   inv    = (int*)bufB;                                // invb/gath2 (dead after gath2)
  int*   bstart = inv + 65536;                               // 4097 ints

  detect_k<<<1, 256, 0, stream>>>(xyz, flag);
  cvtxyz_k<<<1024, 256, 0, stream>>>(xyz, flag, X, Y, Z);
  cvtw_k<<<333, 256, 0, stream>>>(W0, g0, b0, m0, v0, flag, Wb0, sc0, sh0, 291);
  cvtw_k<<<333, 256, 0, stream>>>(W1, g1, b1, m1, v1, flag, Wb1, sc1, sh1, 288);
  cvtw_k<<<333, 256, 0, stream>>>(W2, g2, b2, m2, v2, flag, Wb2, sc2, sh2, 288);
  sort_k<<<NBAT, 1024, 0, stream>>>(X, Y, Z, X2, Y2, Z2, I2);
  fps_k<<<NBAT, 1024, 0, stream>>>(X, Y, Z, X2, Y2, Z2, I2, flag, nxyz, d_out);
  ballq_k<<<1024, 256, 0, stream>>>(X, Y, Z, nxyz, bidx);
  invb_k<<<NBAT, 1024, 0, stream>>>(bidx, inv, bstart);
  gath2_k<<<4096, 256, 0, stream>>>(feat, xyz, flag, inv, bstart, nxyz, bufA);
  gemm_k<<<dim3(512,3), 256, 128*296*2, stream>>>(bufA, 296, Wb0, sc0, sh0, bufB, 288, 10, 296);
  gemm_k<<<dim3(512,3), 256, 128*288*2, stream>>>(bufB, 288, Wb1, sc1, sh1, bufA, 296, 9, 288);
  gemm_k<<<dim3(512,3), 256, 128*296*2, stream>>>(bufA, 296, Wb2, sc2, sh2, bufB, 288, 9, 288);
  maxk_k<<<512, 256, 0, stream>>>(bufB, flag, d_out);
}

// Round 6
// 1065.280 us; speedup vs baseline: 3.2294x; 3.2294x over previous
//
#include <hip/hip_runtime.h>
#include <hip/hip_bf16.h>
#include <string.h>

#define NPT   16384
#define NBAT  16
#define CH    288
#define SP    256
#define KS    16
#define OFF_FEAT 12288L
#define OFF_IND  1191936L

// ---------- helpers ----------
__device__ __forceinline__ float bfbits(unsigned short u){
  unsigned int x = ((unsigned int)u) << 16; float f; __builtin_memcpy(&f,&x,4); return f;
}
__device__ __forceinline__ float ldf(const void* p, long i, int isb){
  if (isb) return __bfloat162float(((const __hip_bfloat16*)p)[i]);
  return ((const float*)p)[i];
}
__device__ __forceinline__ void sto(void* p, long i, float v, int isb){
  if (isb) ((__hip_bfloat16*)p)[i] = __float2bfloat16(v);
  else     ((float*)p)[i] = v;
}
__device__ __forceinline__ void gload_lds(const void* g, void* l){
  __builtin_amdgcn_global_load_lds((const __attribute__((address_space(1))) void*)g,
      (__attribute__((address_space(3))) void*)l, 16, 0, 0);
}
__device__ __forceinline__ unsigned spread4(unsigned x){
  return (x&1u) | ((x&2u)<<2) | ((x&4u)<<4) | ((x&8u)<<6);
}

typedef __attribute__((ext_vector_type(8))) short bf16x8;
typedef __attribute__((ext_vector_type(4))) float f32x4;
typedef __attribute__((ext_vector_type(2))) float f32x2;

// u64 max via DPP row_ror (VALU cross-lane, no DS). Max is associative+commutative,
// so any reduce network gives the bit-exact same result as a shfl butterfly.
template<int CTRL>
__device__ __forceinline__ unsigned long long ror_max64(unsigned long long k){
  int lo2 = __builtin_amdgcn_update_dpp(0, (int)(unsigned)k, CTRL, 0xf, 0xf, false);
  int hi2 = __builtin_amdgcn_update_dpp(0, (int)(unsigned)(k>>32), CTRL, 0xf, 0xf, false);
  unsigned long long o = ((unsigned long long)(unsigned)hi2 << 32) | (unsigned)lo2;
  return o > k ? o : k;
}
__device__ __forceinline__ unsigned long long rowmax64(unsigned long long k){
  k = ror_max64<0x121>(k);   // row_ror:1
  k = ror_max64<0x122>(k);   // row_ror:2
  k = ror_max64<0x124>(k);   // row_ror:4
  k = ror_max64<0x128>(k);   // row_ror:8  -> every lane holds max of its 16-lane row
  return k;
}
__device__ __forceinline__ unsigned long long rl64(unsigned long long v, int l){
  unsigned lo = (unsigned)__builtin_amdgcn_readlane((int)(unsigned)v, l);
  unsigned hi = (unsigned)__builtin_amdgcn_readlane((int)(unsigned)(v>>32), l);
  return (((unsigned long long)hi)<<32) | lo;
}

// ---------- 0. input dtype detection ----------
__global__ void detect_k(const void* __restrict__ xyz, int* __restrict__ flag){
  __shared__ float red[256];
  const int t = threadIdx.x;
  const unsigned short* u = (const unsigned short*)xyz;
  float m = 0.f;
  for (int i = t; i < 4096; i += 256){
    float f = fabsf(bfbits(u[i]));
    if (f != f) f = 1e30f;
    m = fmaxf(m, f);
  }
  red[t] = m; __syncthreads();
  for (int s = 128; s; s >>= 1){ if (t < s) red[t] = fmaxf(red[t], red[t+s]); __syncthreads(); }
  if (t == 0) *flag = (red[0] < 2.0f) ? 1 : 0;
}

// ---------- 0b. xyz -> f32 SoA ----------
__global__ __launch_bounds__(256) void cvtxyz_k(const void* __restrict__ xyz,
    const int* __restrict__ flag, float* __restrict__ X, float* __restrict__ Y,
    float* __restrict__ Z){
  const int n = blockIdx.x*256 + threadIdx.x;       // < 262144 points
  const int isb = *flag;
  float x = ldf(xyz, (long)n*3+0, isb);
  float y = ldf(xyz, (long)n*3+1, isb);
  float z = ldf(xyz, (long)n*3+2, isb);
  X[n] = x; Y[n] = y; Z[n] = z;
}

// ---------- 0c. W -> bf16 [288][296] + BN scale/shift ----------
__global__ __launch_bounds__(256) void cvtw_k(const void* __restrict__ W,
    const void* __restrict__ g, const void* __restrict__ bb,
    const void* __restrict__ m, const void* __restrict__ v,
    const int* __restrict__ flag, __hip_bfloat16* __restrict__ Wbf,
    float* __restrict__ scale, float* __restrict__ shift, int Kin){
  const int isb = *flag;
  const int idx = blockIdx.x*256 + threadIdx.x;
  if (idx < 288*296){
    int o = idx / 296, k = idx - o*296;
    float val = (k < Kin) ? ldf(W, (long)o*Kin + k, isb) : 0.f;
    Wbf[idx] = __float2bfloat16(val);
  }
  if (idx < 288){
    float sc = ldf(g, idx, isb) * rsqrtf(ldf(v, idx, isb) + 1e-5f);
    scale[idx] = sc;
    shift[idx] = ldf(bb, idx, isb) - ldf(m, idx, isb)*sc;
  }
}

// ---------- 0d. Morton bucket sort (per batch): spatial clustering for FPS pruning ----------
__global__ __launch_bounds__(1024) void sort_k(const float* __restrict__ X,
    const float* __restrict__ Y, const float* __restrict__ Z,
    float* __restrict__ X2, float* __restrict__ Y2, float* __restrict__ Z2,
    int* __restrict__ I2){
  __shared__ int hist[4096];
  __shared__ int wtot[16];
  const int b = blockIdx.x, t = threadIdx.x, base = b*NPT;
  for (int j = t; j < 4096; j += 1024) hist[j] = 0;
  __syncthreads();
  int cell[16]; float lx[16], ly[16], lz[16];
  #pragma unroll
  for (int i=0;i<16;i++){
    const int id = t + i*1024;
    float x = X[base+id], y = Y[base+id], z = Z[base+id];
    lx[i]=x; ly[i]=y; lz[i]=z;
    int cx = (int)(x*16.f); cx = cx<0?0:(cx>15?15:cx);
    int cy = (int)(y*16.f); cy = cy<0?0:(cy>15?15:cy);
    int cz = (int)(z*16.f); cz = cz<0?0:(cz>15?15:cz);
    cell[i] = (int)(spread4((unsigned)cx) | (spread4((unsigned)cy)<<1) | (spread4((unsigned)cz)<<2));
    atomicAdd(&hist[cell[i]], 1);
  }
  __syncthreads();
  int s0 = hist[t*4], s1 = hist[t*4+1], s2 = hist[t*4+2], s3 = hist[t*4+3];
  int ls = s0+s1+s2+s3;
  int sc = ls;
  #pragma unroll
  for (int off=1; off<64; off<<=1){
    int o = __shfl_up(sc, off, 64);
    if ((t&63) >= off) sc += o;
  }
  if ((t&63) == 63) wtot[t>>6] = sc;
  __syncthreads();
  int wpre = 0;
  #pragma unroll
  for (int w=0; w<16; w++) wpre += (w < (t>>6)) ? wtot[w] : 0;
  const int ebase = wpre + sc - ls;
  hist[t*4]   = ebase;
  hist[t*4+1] = ebase + s0;
  hist[t*4+2] = ebase + s0 + s1;
  hist[t*4+3] = ebase + s0 + s1 + s2;
  __syncthreads();
  #pragma unroll
  for (int i=0;i<16;i++){
    const int dst = atomicAdd(&hist[cell[i]], 1);
    X2[base+dst] = lx[i]; Y2[base+dst] = ly[i]; Z2[base+dst] = lz[i];
    I2[base+dst] = t + i*1024;
  }
}

// ---------- 1. FPS: DPP argmax + pair prune + winner coords via LDS (static idx) ----------
// Per-pair caches (pk, pcx/pcy/pcz) are updated ONLY inside the unrolled UPD macro
// with literal j (rule #20: no runtime-indexed register arrays -> no scratch).
// The unique winner lane (best==wk; keys unique) publishes coords to slotc; after
// the block reduce, a ballot finds the winning wave and one uniform ds_read
// replaces the dependent global P4 load on the per-iteration critical path.
// Stale-on-skip valid: pruned pairs' dists provably unchanged (bitwise), so their
// cached pk/coords stay exact.
__global__ __launch_bounds__(1024) __attribute__((amdgpu_waves_per_eu(4,4)))
void fps_k(const float* __restrict__ X, const float* __restrict__ Y,
    const float* __restrict__ Z,
    const float* __restrict__ X2, const float* __restrict__ Y2,
    const float* __restrict__ Z2, const int* __restrict__ I2,
    const int* __restrict__ flag, float* __restrict__ nxyz, void* __restrict__ dout){
  #pragma clang fp contract(off)
  const int b = blockIdx.x, t = threadIdx.x;
  const int base = b*NPT;
  const int lane = t & 63, wid = t >> 6;
  f32x2 px[8], py[8], pz[8], ds[8];
  unsigned li2[8];
  unsigned long long pk[8];
  float pcx[8], pcy[8], pcz[8];
  const int p0 = base + wid*1024 + lane;
  #pragma unroll
  for (int j=0;j<8;j++){
    px[j] = (f32x2){X2[p0 + (2*j)*64], X2[p0 + (2*j+1)*64]};
    py[j] = (f32x2){Y2[p0 + (2*j)*64], Y2[p0 + (2*j+1)*64]};
    pz[j] = (f32x2){Z2[p0 + (2*j)*64], Z2[p0 + (2*j+1)*64]};
    unsigned a = 16383u - (unsigned)I2[p0 + (2*j)*64];
    unsigned c = 16383u - (unsigned)I2[p0 + (2*j+1)*64];
    li2[j] = a | (c<<16);
    ds[j] = (f32x2){1e10f, 1e10f};
    pk[j] = 0ull;
    pcx[j] = 0.f; pcy[j] = 0.f; pcz[j] = 0.f;
  }
  // per-pair bboxes; lane holds pair (lane&7)'s bbox
  float pnx=0.f, pxx=0.f, pny=0.f, pxy=0.f, pnz=0.f, pxz=0.f;
  const int myp = lane & 7;
  #pragma unroll
  for (int j=0;j<8;j++){
    float nx = fminf(px[j].x,px[j].y), xx = fmaxf(px[j].x,px[j].y);
    float ny = fminf(py[j].x,py[j].y), xy = fmaxf(py[j].x,py[j].y);
    float nz = fminf(pz[j].x,pz[j].y), xz = fmaxf(pz[j].x,pz[j].y);
    #pragma unroll
    for (int off=32; off; off>>=1){
      nx = fminf(nx, __shfl_xor(nx, off, 64)); xx = fmaxf(xx, __shfl_xor(xx, off, 64));
      ny = fminf(ny, __shfl_xor(ny, off, 64)); xy = fmaxf(xy, __shfl_xor(xy, off, 64));
      nz = fminf(nz, __shfl_xor(nz, off, 64)); xz = fmaxf(xz, __shfl_xor(xz, off, 64));
    }
    if (myp == j){ pnx=nx; pxx=xx; pny=ny; pxy=xy; pnz=nz; pxz=xz; }
  }
  __shared__ unsigned long long slot[2][16];
  __shared__ float4 slotc[2][16];
  __shared__ float ox[SP], oy[SP], oz[SP];
  __shared__ int   oi[SP];
  float cx = X[base], cy = Y[base], cz = Z[base];
  int cur = 0;
  unsigned long long wk = 0ull, best = 0ull;
  float bwx = 0.f, bwy = 0.f, bwz = 0.f;
  float wavemax = 1e30f;
  for (int it=0; it<SP; it++){
    if (t == 0){ ox[it]=cx; oy[it]=cy; oz[it]=cz; oi[it]=cur; }
    float ddx = fmaxf(fmaxf(pnx-cx, cx-pxx), 0.f);
    float ddy = fmaxf(fmaxf(pny-cy, cy-pxy), 0.f);
    float ddz = fmaxf(fmaxf(pnz-cz, cz-pxz), 0.f);
    float lb = ddx*ddx + ddy*ddy; lb = lb + ddz*ddz;
    unsigned mask = (unsigned)__ballot(!(lb * 0.9999f > wavemax)) & 0xffu;
    mask = (unsigned)__builtin_amdgcn_readfirstlane((int)mask);
    if (mask){
      const f32x2 Cx = {cx,cx}, Cy = {cy,cy}, Cz = {cz,cz};
      #define UPD(j) if (mask & (1u<<(j))) { \
        f32x2 dx = px[j]-Cx, dy = py[j]-Cy, dz = pz[j]-Cz; \
        f32x2 m0 = dx*dx, m1 = dy*dy, m2 = dz*dz; \
        f32x2 d2 = (m0+m1)+m2; \
        f32x2 dn = __builtin_elementwise_min(ds[j], d2); \
        ds[j] = dn; \
        unsigned long long k0 = ((unsigned long long)__float_as_uint(dn.x)<<32) | (unsigned long long)(li2[j] & 0xFFFFu); \
        unsigned long long k1 = ((unsigned long long)__float_as_uint(dn.y)<<32) | (unsigned long long)(li2[j] >> 16); \
        bool sx = (k0 > k1); \
        pk[j]  = sx ? k0 : k1; \
        pcx[j] = sx ? px[j].x : px[j].y; \
        pcy[j] = sx ? py[j].x : py[j].y; \
        pcz[j] = sx ? pz[j].x : pz[j].y; }
      UPD(0) UPD(1) UPD(2) UPD(3) UPD(4) UPD(5) UPD(6) UPD(7)
      #undef UPD
      best = pk[0]; bwx = pcx[0]; bwy = pcy[0]; bwz = pcz[0];
      #pragma unroll
      for (int j=1;j<8;j++){
        if (pk[j] > best){ best = pk[j]; bwx = pcx[j]; bwy = pcy[j]; bwz = pcz[j]; }
      }
      unsigned long long rbest = rowmax64(best);
      unsigned long long r0 = rl64(rbest, 0),  r1 = rl64(rbest, 16);
      unsigned long long r2 = rl64(rbest, 32), r3 = rl64(rbest, 48);
      unsigned long long a01 = (r0 > r1) ? r0 : r1;
      unsigned long long a23 = (r2 > r3) ? r2 : r3;
      wk = (a01 > a23) ? a01 : a23;
      wavemax = __uint_as_float((unsigned)(wk >> 32));
    }
    const int p = it & 1;
    if (lane == 0) slot[p][wid] = wk;
    if (best == wk) slotc[p][wid] = make_float4(bwx, bwy, bwz, 0.f);
    __syncthreads();
    unsigned long long sv = slot[p][lane & 15];
    unsigned long long g = rowmax64(sv);
    unsigned long long wb = __ballot(sv == g);
    int w = ((int)__builtin_ctzll(wb)) & 15;
    w = __builtin_amdgcn_readfirstlane(w);
    float4 cc = slotc[p][w];
    cur = 16383 - (int)(unsigned)g;
    cur = __builtin_amdgcn_readfirstlane(cur);
    cx = cc.x; cy = cc.y; cz = cc.z;
  }
  __syncthreads();
  if (t < SP){
    const int isb = *flag;
    const long bs = (long)b*SP + t;
    float fx=ox[t], fy=oy[t], fz=oz[t]; int ii=oi[t];
    nxyz[bs*3+0]=fx; nxyz[bs*3+1]=fy; nxyz[bs*3+2]=fz;
    sto(dout, bs*3+0, fx, isb);
    sto(dout, bs*3+1, fy, isb);
    sto(dout, bs*3+2, fz, isb);
    sto(dout, OFF_IND + bs, (float)ii, isb);
  }
}

// ---------- 2. ball query (SoA f32) ----------
__global__ __launch_bounds__(256) void ballq_k(const float* __restrict__ X,
    const float* __restrict__ Y, const float* __restrict__ Z,
    const float* __restrict__ nxyz, int* __restrict__ bidx){
  #pragma clang fp contract(off)
  const int gw = (blockIdx.x*256 + threadIdx.x) >> 6;
  const int lane = threadIdx.x & 63;
  const int b = gw >> 8, base = b*NPT;
  const float cx = nxyz[gw*3+0], cy = nxyz[gw*3+1], cz = nxyz[gw*3+2];
  int cnt = 0, first = 0; bool havef = false;
  for (int st = 0; st < NPT && cnt < KS; st += 64){
    const int id = st + lane;
    float dx = X[base+id]-cx, dy = Y[base+id]-cy, dz = Z[base+id]-cz;
    float d2 = dx*dx + dy*dy; d2 = d2 + dz*dz;
    unsigned long long mk = __ballot(d2 <= 0.09f);
    if (mk){
      if (!havef){ first = st + __builtin_ctzll(mk); havef = true; }
      int rank = cnt + __popcll(mk & ((1ull<<lane)-1ull));
      if (((mk>>lane)&1ull) && rank < KS) bidx[gw*KS + rank] = id;
      cnt += __popcll(mk);
    }
  }
  if (cnt < KS && lane >= cnt && lane < KS) bidx[gw*KS + lane] = first;
}

// ---------- 3. gather -> h0 [n][296] bf16 via LDS tile ----------
__global__ __launch_bounds__(256) void gather_k(const void* __restrict__ xyz,
    const void* __restrict__ feat, const int* __restrict__ flag,
    const int* __restrict__ bidx, const float* __restrict__ nxyz,
    __hip_bfloat16* __restrict__ h0){
  __shared__ __hip_bfloat16 tile[64*296];
  const int isb = *flag;
  const int t = threadIdx.x, n0 = blockIdx.x*64;
  const int nl = t >> 2, cg = t & 3;
  const int n = n0 + nl, b = n >> 12, s = n >> 4;
  const int id = bidx[n];
  for (int j=0; j<74; j++){
    int c = cg*74 + j;
    float vv = 0.f;
    if (c < 3)       vv = (ldf(xyz, ((long)b*NPT + id)*3 + c, isb) - nxyz[(long)s*3 + c]) / 0.3f;
    else if (c < 291) vv = ldf(feat, ((long)b*CH + (c-3))*(long)NPT + id, isb);
    tile[nl*296 + c] = __float2bfloat16(vv);
  }
  __syncthreads();
  const uint4* src = (const uint4*)tile;
  uint4* dst = (uint4*)((char*)h0 + (long)n0*592);
  for (int j = t; j < 2368; j += 256) dst[j] = src[j];
}

// ---------- 4. MFMA GEMM: Out[n][o] = relu(BN(sum_k A[n][k]*W[o][k])) ----------
__global__ __launch_bounds__(256, 2) void gemm_k(
    const __hip_bfloat16* __restrict__ A, int astr,
    const __hip_bfloat16* __restrict__ W,
    const float* __restrict__ scale, const float* __restrict__ shift,
    __hip_bfloat16* __restrict__ Out, int ostr,
    int ktiles, int kvalid){
  extern __shared__ char lds[];
  const int t = threadIdx.x, lane = t & 63, wid = t >> 6;
  const int wm = wid & 1, wo = wid >> 1;
  const int bx = blockIdx.x, by = blockIdx.y;
  {
    const char* src = (const char*)(A + (long)bx*128*astr);
    const int chunks = (128*astr*2) >> 10;
    for (int c = wid; c < chunks; c += 4)
      gload_lds(src + c*1024 + lane*16, lds + c*1024);
  }
  f32x4 acc[4][3];
  #pragma unroll
  for (int mf=0; mf<4; mf++)
    #pragma unroll
    for (int of=0; of<3; of++) acc[mf][of] = (f32x4){0.f,0.f,0.f,0.f};

  const int mrow  = wm*64 + (lane & 15);
  const int kg    = (lane >> 4) * 8;
  const int obase = by*96 + wo*48 + (lane & 15);
  __syncthreads();

  for (int kt = 0; kt < ktiles; kt++){
    const int k0 = kt*32 + kg;
    const bool z = (k0 >= kvalid);
    const int k0c = z ? 0 : k0;
    bf16x8 a[4], bf[3];
    #pragma unroll
    for (int mf=0; mf<4; mf++)
      a[mf] = *(const bf16x8*)(lds + ((long)(mrow + mf*16)*astr + k0c)*2);
    if (z){
      bf16x8 zz = {0,0,0,0,0,0,0,0};
      #pragma unroll
      for (int mf=0; mf<4; mf++) a[mf] = zz;
    }
    #pragma unroll
    for (int of=0; of<3; of++)
      bf[of] = *(const bf16x8*)(W + (long)(obase + of*16)*296 + k0c);
    #pragma unroll
    for (int mf=0; mf<4; mf++)
      #pragma unroll
      for (int of=0; of<3; of++)
        acc[mf][of] = __builtin_amdgcn_mfma_f32_16x16x32_bf16(a[mf], bf[of], acc[mf][of], 0, 0, 0);
  }

  float sc[3], sh[3];
  #pragma unroll
  for (int of=0; of<3; of++){ sc[of] = scale[obase + of*16]; sh[of] = shift[obase + of*16]; }
  #pragma unroll
  for (int mf=0; mf<4; mf++)
    #pragma unroll
    for (int of=0; of<3; of++)
      #pragma unroll
      for (int r=0; r<4; r++){
        const long row = (long)bx*128 + wm*64 + mf*16 + (lane>>4)*4 + r;
        const int o = obase + of*16;
        float vv = acc[mf][of][r]*sc[of] + sh[of];
        Out[row*ostr + o] = __float2bfloat16(fmaxf(vv, 0.f));
      }
}

// ---------- 5. maxpool over k: h[n][288] -> out[b][o][s] ----------
__global__ __launch_bounds__(256) void maxk_k(const __hip_bfloat16* __restrict__ h,
    const int* __restrict__ flag, void* __restrict__ dout){
  __shared__ __hip_bfloat16 tile[128*288];
  const int isb = *flag;
  const int t = threadIdx.x;
  const int b = blockIdx.x >> 5, s0 = (blockIdx.x & 31)*8;
  const long n0 = (long)b*4096 + (long)s0*16;
  {
    const char* src = (const char*)(h + n0*288);
    for (int c = (t>>6); c < 72; c += 4)
      gload_lds(src + c*1024 + (t&63)*16, (char*)tile + c*1024);
  }
  __syncthreads();
  for (int o = t; o < 288; o += 256){
    float mx[8];
    #pragma unroll
    for (int sl=0; sl<8; sl++){
      float m = -1e30f;
      #pragma unroll
      for (int kk=0; kk<16; kk++)
        m = fmaxf(m, __bfloat162float(tile[(sl*16 + kk)*288 + o]));
      mx[sl] = m;
    }
    const long e0 = OFF_FEAT + (long)b*73728 + (long)o*256 + s0;
    if (isb){
      unsigned short u[8];
      #pragma unroll
      for (int sl=0; sl<8; sl++){
        __hip_bfloat16 hb = __float2bfloat16(mx[sl]);
        __builtin_memcpy(&u[sl], &hb, 2);
      }
      uint4 pk; __builtin_memcpy(&pk, u, 16);
      *(uint4*)((__hip_bfloat16*)dout + e0) = pk;
    } else {
      float* fo = (float*)dout + e0;
      *(float4*)fo     = make_float4(mx[0],mx[1],mx[2],mx[3]);
      *(float4*)(fo+4) = make_float4(mx[4],mx[5],mx[6],mx[7]);
    }
  }
}

extern "C" void kernel_launch(void* const* d_in, const int* in_sizes, int n_in,
                              void* d_out, int out_size, void* d_ws, size_t ws_size,
                              hipStream_t stream){
  const void* xyz  = d_in[0];
  const void* feat = d_in[1];
  const void* W0 = d_in[2];  const void* g0 = d_in[3];  const void* b0 = d_in[4];
  const void* m0 = d_in[5];  const void* v0 = d_in[6];
  const void* W1 = d_in[7];  const void* g1 = d_in[8];  const void* b1 = d_in[9];
  const void* m1 = d_in[10]; const void* v1 = d_in[11];
  const void* W2 = d_in[12]; const void* g2 = d_in[13]; const void* b2 = d_in[14];
  const void* m2 = d_in[15]; const void* v2 = d_in[16];

  char* ws = (char*)d_ws;
  int*   flag  = (int*)ws;                                   // [0,64)
  float* sc0   = (float*)(ws + 64);
  float* sh0   = sc0 + 288;
  float* sc1   = sc0 + 576;  float* sh1 = sc0 + 864;
  float* sc2   = sc0 + 1152; float* sh2 = sc0 + 1440;
  __hip_bfloat16* Wb0 = (__hip_bfloat16*)(ws + 7040);        // 288*296*2 each
  __hip_bfloat16* Wb1 = Wb0 + 288*296;
  __hip_bfloat16* Wb2 = Wb1 + 288*296;                       // ends @ 518528
  float* nxyz = (float*)(ws + 518656);                       // -> 567808
  int*   bidx = (int*)(ws + 567808);                         // -> 829952
  float* X    = (float*)(ws + 1048576);                      // overlaid with bufA (dead after ballq/gather)
  float* Y    = X + NBAT*NPT;
  float* Z    = Y + NBAT*NPT;
  __hip_bfloat16* bufA = (__hip_bfloat16*)(ws + 1048576);    // [65536][296] = 38797312
  __hip_bfloat16* bufB = (__hip_bfloat16*)(ws + 1048576 + 38797312); // [65536][288]
  // Morton-sorted copies, overlaid on bufB (dead before gemm#1 writes bufB)
  float* X2 = (float*)bufB;
  float* Y2 = X2 + NBAT*NPT;
  float* Z2 = Y2 + NBAT*NPT;
  int*   I2 = (int*)(Z2 + NBAT*NPT);                         // 4 MiB total << 37 MiB

  detect_k<<<1, 256, 0, stream>>>(xyz, flag);
  cvtxyz_k<<<1024, 256, 0, stream>>>(xyz, flag, X, Y, Z);
  cvtw_k<<<333, 256, 0, stream>>>(W0, g0, b0, m0, v0, flag, Wb0, sc0, sh0, 291);
  cvtw_k<<<333, 256, 0, stream>>>(W1, g1, b1, m1, v1, flag, Wb1, sc1, sh1, 288);
  cvtw_k<<<333, 256, 0, stream>>>(W2, g2, b2, m2, v2, flag, Wb2, sc2, sh2, 288);
  sort_k<<<NBAT, 1024, 0, stream>>>(X, Y, Z, X2, Y2, Z2, I2);
  fps_k<<<NBAT, 1024, 0, stream>>>(X, Y, Z, X2, Y2, Z2, I2, flag, nxyz, d_out);
  ballq_k<<<1024, 256, 0, stream>>>(X, Y, Z, nxyz, bidx);
  gather_k<<<1024, 256, 0, stream>>>(xyz, feat, flag, bidx, nxyz, bufA);
  gemm_k<<<dim3(512,3), 256, 128*296*2, stream>>>(bufA, 296, Wb0, sc0, sh0, bufB, 288, 10, 296);
  gemm_k<<<dim3(512,3), 256, 128*288*2, stream>>>(bufB, 288, Wb1, sc1, sh1, bufA, 296, 9, 288);
  gemm_k<<<dim3(512,3), 256, 128*296*2, stream>>>(bufA, 296, Wb2, sc2, sh2, bufB, 288, 9, 288);
  maxk_k<<<512, 256, 0, stream>>>(bufB, flag, d_out);
}